// Round 5
// baseline (283.920 us; speedup 1.0000x reference)
//
#include <hip/hip_runtime.h>
#include <math.h>

#define BB 32
#define SS 2048
#define DD 512
#define AD 512

#define BM 128
#define BN 128
#define BK 64    // bf16 elems per K-chunk; row = 128 B = 8 x 16B granules

typedef __bf16 bf16;
typedef __attribute__((ext_vector_type(8))) __bf16 bf16x8;
typedef __attribute__((ext_vector_type(4))) float floatx4;

__device__ inline void async16(const void* g, void* l) {
    __builtin_amdgcn_global_load_lds(
        (const __attribute__((address_space(1))) unsigned int*)g,
        (__attribute__((address_space(3))) unsigned int*)l, 16, 0, 0);
}

// ---------------- K0: probe mask dtype ----------------
__global__ void mask_probe_kernel(const unsigned char* __restrict__ m8,
                                  int* __restrict__ flag) {
    int t = threadIdx.x + blockIdx.x * 256;
    int any = 0;
    for (int i = t; i < BB * SS; i += gridDim.x * 256) {
        if ((i & 3) && m8[i]) any = 1;
    }
    if (__any(any)) {
        if ((threadIdx.x & 63) == 0) atomicOr(flag, 1);
    }
}

// ---------------- K0b: fp32 -> bf16 convert (W2 only, 1 MB) ---------------
__global__ void convert_kernel(const float* __restrict__ src,
                               bf16* __restrict__ dst, int n8) {
    int i = threadIdx.x + blockIdx.x * 256;
    if (i >= n8) return;
    const float4* s4 = (const float4*)src + (size_t)i * 2;
    float4 x = s4[0], y = s4[1];
    bf16x8 o;
    o[0] = (bf16)x.x; o[1] = (bf16)x.y; o[2] = (bf16)x.z; o[3] = (bf16)x.w;
    o[4] = (bf16)y.x; o[5] = (bf16)y.y; o[6] = (bf16)y.z; o[7] = (bf16)y.w;
    *(bf16x8*)(dst + (size_t)i * 8) = o;
}

// ---------------- K1: w1q[b][a] = dot(query[b,:], W1[a,:]) (fp32) ----------
__global__ void w1q_kernel(const float* __restrict__ query,
                           const float* __restrict__ W1,
                           float* __restrict__ w1q) {
    int b = blockIdx.y;
    int a = blockIdx.x * 4 + (threadIdx.x >> 6);
    int lane = threadIdx.x & 63;
    const float4* q4 = (const float4*)(query + (size_t)b * DD) + lane * 2;
    const float4* w4 = (const float4*)(W1 + (size_t)a * DD) + lane * 2;
    float4 qa = q4[0], qb = q4[1];
    float4 wa = w4[0], wb = w4[1];
    float acc = qa.x * wa.x + qa.y * wa.y + qa.z * wa.z + qa.w * wa.w
              + qb.x * wb.x + qb.y * wb.y + qb.z * wb.z + qb.w * wb.w;
#pragma unroll
    for (int off = 32; off > 0; off >>= 1) acc += __shfl_down(acc, off);
    if (lane == 0) w1q[(size_t)b * AD + a] = acc;
}

// ---------------- K2: fused-convert MFMA GEMM + tanh/v epilogue -----------
// A = keys fp32 (converted in-register during staging), B = W2b bf16 via
// async16. Round-3 2-barrier skeleton, BK=64 (32 MFMA/wave/barrier).
// XOR swizzle at 16B granules: LDS position p of row r holds source granule
// p^(r&7); frag read for k-granule g reads position g^(r&7). A-writes go
// through ds_write_b128 at position g^(r&7) (lanes w/ equal g -> distinct
// banks). A-prefetch fp32 loads for chunk c+1 issued AFTER barrier 2 so the
// next barrier's vmcnt drain has frag-read+MFMA cover.
__global__ __launch_bounds__(256, 3)
void gemm_scores_fused(const float* __restrict__ keys,
                       const bf16* __restrict__ W2b,
                       const float* __restrict__ w1q,
                       const float* __restrict__ v,
                       float* __restrict__ partial) {
    __shared__ bf16 a_lds[BM * BK];   // 16 KB
    __shared__ bf16 b_lds[BN * BK];   // 16 KB
    __shared__ float s_red[BM];

    const int t    = threadIdx.x;
    const int lane = t & 63;
    const int w    = t >> 6;
    const int ml   = lane & 15;
    const int kg   = lane >> 4;
    const int b    = blockIdx.z;
    const int a0   = blockIdx.x * BN;   // a-tile fastest: keys reuse in L2/L3
    const int s0   = blockIdx.y * BM;
    const int m_off = (w & 1) * 64;
    const int n_off = (w >> 1) * 64;

    const float* Ablk = keys + ((size_t)b * SS + s0) * DD;
    const bf16*  Bblk = W2b + (size_t)a0 * DD;

    if (t < BM) s_red[t] = 0.f;

    floatx4 acc[4][4];
#pragma unroll
    for (int mi = 0; mi < 4; ++mi)
#pragma unroll
        for (int ni = 0; ni < 4; ++ni)
            acc[mi][ni] = (floatx4)(0.f);

    // per-thread staging: 4 granules each for A and B.
    // granule lin = t + 256*i; r = lin>>3, g = lin&7.
    float4 ga[4][2];
#pragma unroll
    for (int i = 0; i < 4; ++i) {
        int lin = t + 256 * i;
        int r = lin >> 3, g = lin & 7;
        const float* p = Ablk + (size_t)r * DD + g * 8;
        ga[i][0] = *(const float4*)p;
        ga[i][1] = *(const float4*)(p + 4);
    }

    const int NCHUNK = DD / BK;   // 8
    for (int c = 0; c < NCHUNK; ++c) {
        __syncthreads();   // barrier 1: prev chunk's frag reads done
        // A: convert prefetched regs, write swizzled granule
#pragma unroll
        for (int i = 0; i < 4; ++i) {
            int lin = t + 256 * i;
            int r = lin >> 3, g = lin & 7;
            bf16x8 o;
            o[0] = (bf16)ga[i][0].x; o[1] = (bf16)ga[i][0].y;
            o[2] = (bf16)ga[i][0].z; o[3] = (bf16)ga[i][0].w;
            o[4] = (bf16)ga[i][1].x; o[5] = (bf16)ga[i][1].y;
            o[6] = (bf16)ga[i][1].z; o[7] = (bf16)ga[i][1].w;
            *(bf16x8*)&a_lds[r * BK + (g ^ (r & 7)) * 8] = o;
        }
        // B: async16, swizzled source granule, wave-uniform LDS base
#pragma unroll
        for (int i = 0; i < 4; ++i) {
            int lin = t + 256 * i;
            int r = lin >> 3, cc = lin & 7, cs = cc ^ (r & 7);
            async16(Bblk + (size_t)r * DD + c * BK + cs * 8,
                    &b_lds[(256 * i + w * 64) * 8]);
        }
        __syncthreads();   // barrier 2: drains A lgkm + B vmcnt

        // A-prefetch for next chunk: issued here so the NEXT barrier-1 drain
        // is covered by this chunk's frag reads + MFMA.
        if (c + 1 < NCHUNK) {
            const int d0 = (c + 1) * BK;
#pragma unroll
            for (int i = 0; i < 4; ++i) {
                int lin = t + 256 * i;
                int r = lin >> 3, g = lin & 7;
                const float* p = Ablk + (size_t)r * DD + d0 + g * 8;
                ga[i][0] = *(const float4*)p;
                ga[i][1] = *(const float4*)(p + 4);
            }
        }

#pragma unroll
        for (int ks = 0; ks < 2; ++ks) {
            bf16x8 af[4], bfr[4];
#pragma unroll
            for (int mi = 0; mi < 4; ++mi) {
                int R = m_off + mi * 16 + ml;
                int pos = (ks * 4 + kg) ^ (R & 7);
                af[mi] = *(const bf16x8*)&a_lds[R * BK + pos * 8];
            }
#pragma unroll
            for (int ni = 0; ni < 4; ++ni) {
                int R = n_off + ni * 16 + ml;
                int pos = (ks * 4 + kg) ^ (R & 7);
                bfr[ni] = *(const bf16x8*)&b_lds[R * BK + pos * 8];
            }
#pragma unroll
            for (int mi = 0; mi < 4; ++mi)
#pragma unroll
                for (int ni = 0; ni < 4; ++ni)
                    acc[mi][ni] = __builtin_amdgcn_mfma_f32_16x16x32_bf16(
                        af[mi], bfr[ni], acc[mi][ni], 0, 0, 0);
        }
    }

    // epilogue: tanh + v-weight, reduce over this block's 128 a's per s
    float w1qa[4], va[4];
#pragma unroll
    for (int ni = 0; ni < 4; ++ni) {
        int a = a0 + n_off + ni * 16 + ml;
        w1qa[ni] = w1q[(size_t)b * AD + a];
        va[ni]   = v[a];
    }
#pragma unroll
    for (int mi = 0; mi < 4; ++mi) {
#pragma unroll
        for (int reg = 0; reg < 4; ++reg) {
            float p = 0.f;
#pragma unroll
            for (int ni = 0; ni < 4; ++ni) {
                float x = acc[mi][ni][reg] + w1qa[ni];
                float th = 1.f - 2.f / (1.f + __expf(2.f * x));
                p = fmaf(th, va[ni], p);
            }
            p += __shfl_xor(p, 1);
            p += __shfl_xor(p, 2);
            p += __shfl_xor(p, 4);
            p += __shfl_xor(p, 8);
            if (ml == 0)
                atomicAdd(&s_red[m_off + mi * 16 + kg * 4 + reg], p);
        }
    }
    __syncthreads();
    if (t < BM)
        partial[(((size_t)b * SS) + s0 + t) * 4 + blockIdx.x] = s_red[t];
}

// ---------------- K3: combine partials + masked softmax over s ------------
__global__ void softmax_kernel(const float* __restrict__ partial,
                               const int* __restrict__ mask_i32,
                               const unsigned char* __restrict__ mask_u8,
                               const int* __restrict__ flag,
                               float* __restrict__ out) {
    const int b = blockIdx.x;
    const int t = threadIdx.x;
    __shared__ float rmax[4], rsum[4];
    const int wid = t >> 6, lane = t & 63;

    float sv[8]; int mv[8];
    const int bytes = (*flag != 0);
#pragma unroll
    for (int k = 0; k < 8; ++k) {
        int i = t + 256 * k;
        float4 p4 = *(const float4*)(partial + ((size_t)b * SS + i) * 4);
        sv[k] = (p4.x + p4.y) + (p4.z + p4.w);
        mv[k] = bytes ? (int)mask_u8[(size_t)b * SS + i]
                      : mask_i32[(size_t)b * SS + i];
    }

    float mx = -INFINITY;
#pragma unroll
    for (int k = 0; k < 8; ++k) mx = fmaxf(mx, mv[k] ? sv[k] : -INFINITY);
#pragma unroll
    for (int off = 32; off > 0; off >>= 1) mx = fmaxf(mx, __shfl_xor(mx, off));
    if (lane == 0) rmax[wid] = mx;
    __syncthreads();
    mx = fmaxf(fmaxf(rmax[0], rmax[1]), fmaxf(rmax[2], rmax[3]));

    float ev[8]; float sum = 0.f;
#pragma unroll
    for (int k = 0; k < 8; ++k) {
        ev[k] = mv[k] ? __expf(sv[k] - mx) : 0.f;
        sum += ev[k];
    }
#pragma unroll
    for (int off = 32; off > 0; off >>= 1) sum += __shfl_xor(sum, off);
    if (lane == 0) rsum[wid] = sum;
    __syncthreads();
    sum = (rsum[0] + rsum[1]) + (rsum[2] + rsum[3]);
    float inv = 1.f / sum;
#pragma unroll
    for (int k = 0; k < 8; ++k)
        out[(size_t)b * SS + t + 256 * k] = ev[k] * inv;
}

extern "C" void kernel_launch(void* const* d_in, const int* in_sizes, int n_in,
                              void* d_out, int out_size, void* d_ws, size_t ws_size,
                              hipStream_t stream) {
    const float* query = (const float*)d_in[0];
    const float* keys  = (const float*)d_in[1];
    const void*  mask  = d_in[2];
    const float* W1    = (const float*)d_in[3];
    const float* W2    = (const float*)d_in[4];
    const float* v     = (const float*)d_in[5];
    float* out = (float*)d_out;

    // ws layout (bytes): [flag 256][w1q 64K][partial 1M][W2b 0.5M]
    char* wsb = (char*)d_ws;
    int*   flag    = (int*)wsb;
    float* w1q     = (float*)(wsb + 256);
    float* partial = (float*)(wsb + 256 + 65536);
    bf16*  W2b     = (bf16*)(wsb + 256 + 65536 + 1048576);

    hipMemsetAsync(flag, 0, 4, stream);
    mask_probe_kernel<<<64, 256, 0, stream>>>((const unsigned char*)mask, flag);
    w1q_kernel<<<dim3(AD / 4, BB), 256, 0, stream>>>(query, W1, w1q);
    convert_kernel<<<AD * DD / 8 / 256, 256, 0, stream>>>(W2, W2b, AD * DD / 8);
    gemm_scores_fused<<<dim3(AD / BN, SS / BM, BB), 256, 0, stream>>>(
        keys, W2b, w1q, v, partial);
    softmax_kernel<<<BB, 256, 0, stream>>>(partial, (const int*)mask,
                                           (const unsigned char*)mask, flag, out);
}

// Round 6
// 263.649 us; speedup vs baseline: 1.0769x; 1.0769x over previous
//
#include <hip/hip_runtime.h>
#include <math.h>

#define BB 32
#define SS 2048
#define DD 512
#define AD 512

#define BM 128
#define BN 128
#define BK 64    // bf16 elems per K-chunk; row = 128 B = 8 x 16B granules

typedef __bf16 bf16;
typedef __attribute__((ext_vector_type(8))) __bf16 bf16x8;
typedef __attribute__((ext_vector_type(4))) __bf16 bf16x4;
typedef __attribute__((ext_vector_type(4))) float floatx4;

__device__ inline void async16(const void* g, void* l) {
    __builtin_amdgcn_global_load_lds(
        (const __attribute__((address_space(1))) unsigned int*)g,
        (__attribute__((address_space(3))) unsigned int*)l, 16, 0, 0);
}

// ---------------- K1: fused prep ----------------
// blocks [0, NCV)            : fp32->bf16 convert of keys then W2
// blocks [NCV, NCV+64)       : mask dtype probe
// blocks [NCV+64, NCV+64+4096): w1q[b][a] = dot(query[b,:], W1[a,:])
#define NK8 (BB * SS * DD / 8)
#define NW8 (AD * DD / 8)
#define NCV ((NK8 + NW8) / 256)
__global__ void prep_kernel(const float* __restrict__ keys,
                            const float* __restrict__ W2,
                            bf16* __restrict__ keysb,
                            bf16* __restrict__ W2b,
                            const unsigned char* __restrict__ m8,
                            int* __restrict__ flag,
                            const float* __restrict__ query,
                            const float* __restrict__ W1,
                            float* __restrict__ w1q) {
    const int bid = blockIdx.x;
    if (bid < NCV) {
        int i = threadIdx.x + bid * 256;
        const float* src;
        bf16* dst;
        int j;
        if (i < NK8) { src = keys; dst = keysb; j = i; }
        else         { src = W2;   dst = W2b;   j = i - NK8; }
        const float4* s4 = (const float4*)src + (size_t)j * 2;
        float4 x = s4[0], y = s4[1];
        bf16x8 o;
        o[0] = (bf16)x.x; o[1] = (bf16)x.y; o[2] = (bf16)x.z; o[3] = (bf16)x.w;
        o[4] = (bf16)y.x; o[5] = (bf16)y.y; o[6] = (bf16)y.z; o[7] = (bf16)y.w;
        *(bf16x8*)(dst + (size_t)j * 8) = o;
    } else if (bid < NCV + 64) {
        int t = threadIdx.x + (bid - NCV) * 256;
        int any = 0;
        for (int i = t; i < BB * SS; i += 64 * 256)
            if ((i & 3) && m8[i]) any = 1;
        if (__any(any)) {
            if ((threadIdx.x & 63) == 0) atomicOr(flag, 1);
        }
    } else {
        int id = bid - NCV - 64;           // 0..4095
        int b = id >> 7;
        int a = (id & 127) * 4 + (threadIdx.x >> 6);
        int lane = threadIdx.x & 63;
        const float4* q4 = (const float4*)(query + (size_t)b * DD) + lane * 2;
        const float4* w4 = (const float4*)(W1 + (size_t)a * DD) + lane * 2;
        float4 qa = q4[0], qb = q4[1];
        float4 wa = w4[0], wb = w4[1];
        float acc = qa.x * wa.x + qa.y * wa.y + qa.z * wa.z + qa.w * wa.w
                  + qb.x * wb.x + qb.y * wb.y + qb.z * wb.z + qb.w * wb.w;
#pragma unroll
        for (int off = 32; off > 0; off >>= 1) acc += __shfl_down(acc, off);
        if (lane == 0) w1q[(size_t)b * AD + a] = acc;
    }
}

// ---------------- K2: async16 MFMA GEMM + fused tanh/v epilogue -----------
// Round-3 skeleton: bf16 A/B via async16, BK=64, 2 barriers/chunk,
// 16B-granule XOR swizzle c^(r&7) (conflict-free staging + frag reads).
// 1D grid with XCD-grouping swizzle: the 4 a-tile blocks of one keys tile
// share lin&7 (same XCD under round-robin) and are dispatch-adjacent.
// Epilogue: quad shuffle-reduce then direct global store of 8 partials/row
// (4 a-tiles x 2 n-halves) -- no LDS atomics, no extra barriers.
__global__ __launch_bounds__(256, 4)
void gemm_scores_mfma(const bf16* __restrict__ keysb,
                      const bf16* __restrict__ W2b,
                      const float* __restrict__ w1q,
                      const float* __restrict__ v,
                      float* __restrict__ partial) {
    __shared__ bf16 a_lds[BM * BK];   // 16 KB
    __shared__ bf16 b_lds[BN * BK];   // 16 KB

    const int t    = threadIdx.x;
    const int lane = t & 63;
    const int w    = t >> 6;
    const int ml   = lane & 15;
    const int kg   = lane >> 4;

    // grid decode: lin -> (keys-tile kt, a_tile) with lin&7 == kt&7
    const int lin    = blockIdx.x;
    const int x8     = lin & 7;
    const int hi     = lin >> 3;
    const int a_tile = hi & 3;
    const int kt     = x8 + ((hi >> 2) << 3);   // 0..511
    const int b      = kt >> 4;
    const int s0     = (kt & 15) * BM;
    const int a0     = a_tile * BN;

    const int m_off = (w & 1) * 64;
    const int n_off = (w >> 1) * 64;

    const bf16* Ablk = keysb + ((size_t)b * SS + s0) * DD;
    const bf16* Bblk = W2b + (size_t)a0 * DD;

    floatx4 acc[4][4];
#pragma unroll
    for (int mi = 0; mi < 4; ++mi)
#pragma unroll
        for (int ni = 0; ni < 4; ++ni)
            acc[mi][ni] = (floatx4)(0.f);

    const int NCHUNK = DD / BK;   // 8
    for (int c = 0; c < NCHUNK; ++c) {
        const int d0 = c * BK;
        __syncthreads();   // previous chunk's frag reads done
#pragma unroll
        for (int i = 0; i < 4; ++i) {
            int lin2 = t + 256 * i;
            int r = lin2 >> 3, cc = lin2 & 7, cs = cc ^ (r & 7);
            async16(Ablk + (size_t)r * DD + d0 + cs * 8,
                    &a_lds[(256 * i + w * 64) * 8]);
            async16(Bblk + (size_t)r * DD + d0 + cs * 8,
                    &b_lds[(256 * i + w * 64) * 8]);
        }
        __syncthreads();   // staging drained

#pragma unroll
        for (int ks = 0; ks < 2; ++ks) {
            bf16x8 af[4], bfr[4];
#pragma unroll
            for (int mi = 0; mi < 4; ++mi) {
                int R = m_off + mi * 16 + ml;
                int pos = (ks * 4 + kg) ^ (R & 7);
                af[mi] = *(const bf16x8*)&a_lds[R * BK + pos * 8];
            }
#pragma unroll
            for (int ni = 0; ni < 4; ++ni) {
                int R = n_off + ni * 16 + ml;
                int pos = (ks * 4 + kg) ^ (R & 7);
                bfr[ni] = *(const bf16x8*)&b_lds[R * BK + pos * 8];
            }
#pragma unroll
            for (int mi = 0; mi < 4; ++mi)
#pragma unroll
                for (int ni = 0; ni < 4; ++ni)
                    acc[mi][ni] = __builtin_amdgcn_mfma_f32_16x16x32_bf16(
                        af[mi], bfr[ni], acc[mi][ni], 0, 0, 0);
        }
    }

    // epilogue: tanh + v-weight; reduce over this wave's 64 a's per s-row,
    // store partial[(b,s)*8 + a_tile*2 + n_half] directly (no LDS).
    float w1qa[4], va[4];
#pragma unroll
    for (int ni = 0; ni < 4; ++ni) {
        int a = a0 + n_off + ni * 16 + ml;
        w1qa[ni] = w1q[(size_t)b * AD + a];
        va[ni]   = v[a];
    }
    const int slot = a_tile * 2 + (w >> 1);
#pragma unroll
    for (int mi = 0; mi < 4; ++mi) {
#pragma unroll
        for (int reg = 0; reg < 4; ++reg) {
            float p = 0.f;
#pragma unroll
            for (int ni = 0; ni < 4; ++ni) {
                float x = acc[mi][ni][reg] + w1qa[ni];
                float th = 1.f - 2.f / (1.f + __expf(2.f * x));
                p = fmaf(th, va[ni], p);
            }
            p += __shfl_xor(p, 1);
            p += __shfl_xor(p, 2);
            p += __shfl_xor(p, 4);
            p += __shfl_xor(p, 8);
            if (ml == 0) {
                int row = m_off + mi * 16 + kg * 4 + reg;
                partial[((size_t)b * SS + s0 + row) * 8 + slot] = p;
            }
        }
    }
}

// ---------------- K2-fallback (round-2 fused-convert kernel) --------------
#define FBK 32
#define FLDK (FBK + 8)
__global__ __launch_bounds__(256, 2)
void gemm_scores_fallback(const float* __restrict__ keys,
                          const float* __restrict__ W2,
                          const float* __restrict__ w1q,
                          const float* __restrict__ v,
                          float* __restrict__ partial) {
    __shared__ bf16 a_lds[BM][FLDK];
    __shared__ bf16 b_lds[BN][FLDK];
    __shared__ float s_red[BM];

    const int t    = threadIdx.x;
    const int lane = t & 63;
    const int w    = t >> 6;
    const int ml   = lane & 15;
    const int kg   = lane >> 4;
    const int b    = blockIdx.z;
    const int s0   = blockIdx.x * BM;
    const int a0   = blockIdx.y * BN;
    const int m_off = (w & 1) * 64;
    const int n_off = (w >> 1) * 64;

    const float* Ablk = keys + ((size_t)b * SS + s0) * DD;
    const float* Bblk = W2 + (size_t)a0 * DD;

    if (t < BM) s_red[t] = 0.f;

    floatx4 acc[4][4];
#pragma unroll
    for (int mi = 0; mi < 4; ++mi)
#pragma unroll
        for (int ni = 0; ni < 4; ++ni)
            acc[mi][ni] = (floatx4)(0.f);

    float4 ga[4], gb[4];
#pragma unroll
    for (int i = 0; i < 4; ++i) {
        int idx = t + 256 * i;
        int r = idx >> 3, c = idx & 7;
        ga[i] = *(const float4*)(Ablk + (size_t)r * DD + c * 4);
        gb[i] = *(const float4*)(Bblk + (size_t)r * DD + c * 4);
    }

    for (int chunk = 0; chunk < DD / FBK; ++chunk) {
        __syncthreads();
#pragma unroll
        for (int i = 0; i < 4; ++i) {
            int idx = t + 256 * i;
            int r = idx >> 3, c = idx & 7;
            bf16x4 pa, pb;
            pa[0] = (bf16)ga[i].x; pa[1] = (bf16)ga[i].y;
            pa[2] = (bf16)ga[i].z; pa[3] = (bf16)ga[i].w;
            pb[0] = (bf16)gb[i].x; pb[1] = (bf16)gb[i].y;
            pb[2] = (bf16)gb[i].z; pb[3] = (bf16)gb[i].w;
            *(bf16x4*)&a_lds[r][c * 4] = pa;
            *(bf16x4*)&b_lds[r][c * 4] = pb;
        }
        __syncthreads();
        if (chunk < DD / FBK - 1) {
            int d0 = (chunk + 1) * FBK;
#pragma unroll
            for (int i = 0; i < 4; ++i) {
                int idx = t + 256 * i;
                int r = idx >> 3, c = idx & 7;
                ga[i] = *(const float4*)(Ablk + (size_t)r * DD + d0 + c * 4);
                gb[i] = *(const float4*)(Bblk + (size_t)r * DD + d0 + c * 4);
            }
        }
        bf16x8 af[4], bfr[4];
#pragma unroll
        for (int mi = 0; mi < 4; ++mi)
            af[mi] = *(const bf16x8*)&a_lds[m_off + mi * 16 + ml][kg * 8];
#pragma unroll
        for (int ni = 0; ni < 4; ++ni)
            bfr[ni] = *(const bf16x8*)&b_lds[n_off + ni * 16 + ml][kg * 8];
#pragma unroll
        for (int mi = 0; mi < 4; ++mi)
#pragma unroll
            for (int ni = 0; ni < 4; ++ni)
                acc[mi][ni] = __builtin_amdgcn_mfma_f32_16x16x32_bf16(
                    af[mi], bfr[ni], acc[mi][ni], 0, 0, 0);
    }

    float w1qa[4], va[4];
#pragma unroll
    for (int ni = 0; ni < 4; ++ni) {
        int a = a0 + n_off + ni * 16 + ml;
        w1qa[ni] = w1q[(size_t)b * AD + a];
        va[ni]   = v[a];
    }
#pragma unroll
    for (int mi = 0; mi < 4; ++mi) {
#pragma unroll
        for (int reg = 0; reg < 4; ++reg) {
            float p = 0.f;
#pragma unroll
            for (int ni = 0; ni < 4; ++ni) {
                float x = acc[mi][ni][reg] + w1qa[ni];
                float th = 1.f - 2.f / (1.f + __expf(2.f * x));
                p = fmaf(th, va[ni], p);
            }
            p += __shfl_xor(p, 1);
            p += __shfl_xor(p, 2);
            p += __shfl_xor(p, 4);
            p += __shfl_xor(p, 8);
            if (ml == 0)
                atomicAdd(&s_red[m_off + mi * 16 + kg * 4 + reg], p);
        }
    }
    __syncthreads();
    if (t < BM)
        partial[(((size_t)b * SS) + s0 + t) * 8 + blockIdx.y * 2] = s_red[t];
}

// ---------------- K3: combine 8 partials + masked softmax over s ----------
__global__ void softmax_kernel(const float* __restrict__ partial,
                               const int* __restrict__ mask_i32,
                               const unsigned char* __restrict__ mask_u8,
                               const int* __restrict__ flag,
                               float* __restrict__ out) {
    const int b = blockIdx.x;
    const int t = threadIdx.x;
    __shared__ float rmax[4], rsum[4];
    const int wid = t >> 6, lane = t & 63;

    float sv[8]; int mv[8];
    const int bytes = (*flag != 0);
#pragma unroll
    for (int k = 0; k < 8; ++k) {
        int i = t + 256 * k;
        const float4* p4 = (const float4*)(partial + ((size_t)b * SS + i) * 8);
        float4 pa = p4[0], pb = p4[1];
        sv[k] = ((pa.x + pa.y) + (pa.z + pa.w)) + ((pb.x + pb.y) + (pb.z + pb.w));
        mv[k] = bytes ? (int)mask_u8[(size_t)b * SS + i]
                      : mask_i32[(size_t)b * SS + i];
    }

    float mx = -INFINITY;
#pragma unroll
    for (int k = 0; k < 8; ++k) mx = fmaxf(mx, mv[k] ? sv[k] : -INFINITY);
#pragma unroll
    for (int off = 32; off > 0; off >>= 1) mx = fmaxf(mx, __shfl_xor(mx, off));
    if (lane == 0) rmax[wid] = mx;
    __syncthreads();
    mx = fmaxf(fmaxf(rmax[0], rmax[1]), fmaxf(rmax[2], rmax[3]));

    float ev[8]; float sum = 0.f;
#pragma unroll
    for (int k = 0; k < 8; ++k) {
        ev[k] = mv[k] ? __expf(sv[k] - mx) : 0.f;
        sum += ev[k];
    }
#pragma unroll
    for (int off = 32; off > 0; off >>= 1) sum += __shfl_xor(sum, off);
    if (lane == 0) rsum[wid] = sum;
    __syncthreads();
    sum = (rsum[0] + rsum[1]) + (rsum[2] + rsum[3]);
    float inv = 1.f / sum;
#pragma unroll
    for (int k = 0; k < 8; ++k)
        out[(size_t)b * SS + t + 256 * k] = ev[k] * inv;
}

extern "C" void kernel_launch(void* const* d_in, const int* in_sizes, int n_in,
                              void* d_out, int out_size, void* d_ws, size_t ws_size,
                              hipStream_t stream) {
    const float* query = (const float*)d_in[0];
    const float* keys  = (const float*)d_in[1];
    const void*  mask  = d_in[2];
    const float* W1    = (const float*)d_in[3];
    const float* W2    = (const float*)d_in[4];
    const float* v     = (const float*)d_in[5];
    float* out = (float*)d_out;

    // ws layout (bytes): [flag 256][w1q 64K][partial 2M][keysb 64M][W2b 0.5M]
    char* wsb = (char*)d_ws;
    int*   flag    = (int*)wsb;
    float* w1q     = (float*)(wsb + 256);
    float* partial = (float*)(wsb + 256 + 65536);
    bf16*  keysb   = (bf16*)(wsb + 256 + 65536 + 2097152);
    bf16*  W2b     = (bf16*)(wsb + 256 + 65536 + 2097152 + (size_t)BB * SS * DD * 2);
    size_t need = 256 + 65536 + 2097152 + (size_t)BB * SS * DD * 2 + (size_t)AD * DD * 2;

    hipMemsetAsync(flag, 0, 4, stream);
    if (ws_size >= need) {
        prep_kernel<<<NCV + 64 + 4096, 256, 0, stream>>>(
            keys, W2, keysb, W2b, (const unsigned char*)mask, flag, query, W1, w1q);
        gemm_scores_mfma<<<(SS / BM) * (AD / BN) * BB, 256, 0, stream>>>(
            keysb, W2b, w1q, v, partial);
    } else {
        hipMemsetAsync(partial, 0, (size_t)BB * SS * 8 * 4, stream);
        prep_kernel<<<64 + 4096, 256, 0, stream>>>(   // skip convert range
            keys, W2, keysb, W2b, (const unsigned char*)mask, flag, query, W1, w1q);
        // note: the small grid shifts block ranges; relaunch probe+w1q properly:
        // (prep with full ranges requires ws for converts, so do fallback GEMM)
        gemm_scores_fallback<<<dim3(SS / BM, AD / BN, BB), 256, 0, stream>>>(
            keys, W2, w1q, v, partial);
    }
    softmax_kernel<<<BB, 256, 0, stream>>>(partial, (const int*)mask,
                                           (const unsigned char*)mask, flag, out);
}

// Round 7
// 245.183 us; speedup vs baseline: 1.1580x; 1.0753x over previous
//
#include <hip/hip_runtime.h>
#include <math.h>

#define BB 32
#define SS 2048
#define DD 512
#define AD 512

#define BM 128
#define BN 128
#define BK 64    // K elems per chunk. A row: 64 fp32 = 256 B = 16 granules;
                 // B row: 64 bf16 = 128 B = 8 granules (granule = 16 B)

typedef __bf16 bf16;
typedef __attribute__((ext_vector_type(8))) __bf16 bf16x8;
typedef __attribute__((ext_vector_type(4))) __bf16 bf16x4;
typedef __attribute__((ext_vector_type(4))) float floatx4;

__device__ inline void async16(const void* g, void* l) {
    __builtin_amdgcn_global_load_lds(
        (const __attribute__((address_space(1))) unsigned int*)g,
        (__attribute__((address_space(3))) unsigned int*)l, 16, 0, 0);
}

// ---------------- K1: fused prep ----------------
// blocks [0, NCV)             : fp32->bf16 convert of W2 (1 MB only)
// blocks [NCV, NCV+64)        : mask dtype probe
// blocks [NCV+64, NCV+64+4096): w1q[b][a] = dot(query[b,:], W1[a,:])
#define NW8 (AD * DD / 8)
#define NCV (NW8 / 256)   // 128
__global__ void prep_kernel(const float* __restrict__ W2,
                            bf16* __restrict__ W2b,
                            const unsigned char* __restrict__ m8,
                            int* __restrict__ flag,
                            const float* __restrict__ query,
                            const float* __restrict__ W1,
                            float* __restrict__ w1q) {
    const int bid = blockIdx.x;
    if (bid < NCV) {
        int j = threadIdx.x + bid * 256;
        const float4* s4 = (const float4*)W2 + (size_t)j * 2;
        float4 x = s4[0], y = s4[1];
        bf16x8 o;
        o[0] = (bf16)x.x; o[1] = (bf16)x.y; o[2] = (bf16)x.z; o[3] = (bf16)x.w;
        o[4] = (bf16)y.x; o[5] = (bf16)y.y; o[6] = (bf16)y.z; o[7] = (bf16)y.w;
        *(bf16x8*)(W2b + (size_t)j * 8) = o;
    } else if (bid < NCV + 64) {
        int t = threadIdx.x + (bid - NCV) * 256;
        int any = 0;
        for (int i = t; i < BB * SS; i += 64 * 256)
            if ((i & 3) && m8[i]) any = 1;
        if (__any(any)) {
            if ((threadIdx.x & 63) == 0) atomicOr(flag, 1);
        }
    } else {
        int id = bid - NCV - 64;           // 0..4095
        int b = id >> 7;
        int a = (id & 127) * 4 + (threadIdx.x >> 6);
        int lane = threadIdx.x & 63;
        const float4* q4 = (const float4*)(query + (size_t)b * DD) + lane * 2;
        const float4* w4 = (const float4*)(W1 + (size_t)a * DD) + lane * 2;
        float4 qa = q4[0], qb = q4[1];
        float4 wa = w4[0], wb = w4[1];
        float acc = qa.x * wa.x + qa.y * wa.y + qa.z * wa.z + qa.w * wa.w
                  + qb.x * wb.x + qb.y * wb.y + qb.z * wb.z + qb.w * wb.w;
#pragma unroll
        for (int off = 32; off > 0; off >>= 1) acc += __shfl_down(acc, off);
        if (lane == 0) w1q[(size_t)b * AD + a] = acc;
    }
}

// ---------------- K2: fp32-A async16 MFMA GEMM + tanh/v epilogue ----------
// A = keys fp32 staged RAW via async16 (32 KB tile), converted to bf16 at
// frag read (2x ds_read_b128 + v_cvt, overlaps MFMA). B = W2b bf16 async16.
// Round-6 skeleton otherwise: BK=64, 2 barriers/chunk, XOR granule swizzle
// (A: pos = g ^ (r&15) over 16-granule rows; B: g ^ (r&7) over 8), XCD-
// grouped 1-D grid, direct-store epilogue.
__global__ __launch_bounds__(256, 3)
void gemm_scores_mfma(const float* __restrict__ keys,
                      const bf16* __restrict__ W2b,
                      const float* __restrict__ w1q,
                      const float* __restrict__ v,
                      float* __restrict__ partial) {
    __shared__ float a_lds[BM * BK];   // 32 KB fp32
    __shared__ bf16  b_lds[BN * BK];   // 16 KB bf16

    const int t    = threadIdx.x;
    const int lane = t & 63;
    const int w    = t >> 6;
    const int ml   = lane & 15;
    const int kg   = lane >> 4;

    // grid decode: lin -> (keys-tile kt, a_tile) with lin&7 == kt&7 (XCD)
    const int lin    = blockIdx.x;
    const int x8     = lin & 7;
    const int hi     = lin >> 3;
    const int a_tile = hi & 3;
    const int kt     = x8 + ((hi >> 2) << 3);   // 0..511
    const int b      = kt >> 4;
    const int s0     = (kt & 15) * BM;
    const int a0     = a_tile * BN;

    const int m_off = (w & 1) * 64;
    const int n_off = (w >> 1) * 64;

    const float* Ablk = keys + ((size_t)b * SS + s0) * DD;
    const bf16*  Bblk = W2b + (size_t)a0 * DD;

    floatx4 acc[4][4];
#pragma unroll
    for (int mi = 0; mi < 4; ++mi)
#pragma unroll
        for (int ni = 0; ni < 4; ++ni)
            acc[mi][ni] = (floatx4)(0.f);

    const int NCHUNK = DD / BK;   // 8
    for (int c = 0; c < NCHUNK; ++c) {
        const int d0 = c * BK;
        __syncthreads();   // previous chunk's frag reads done
        // A: 2048 granules (16B = 4 fp32), 8 per thread
#pragma unroll
        for (int i = 0; i < 8; ++i) {
            int g = t + 256 * i;
            int r = g >> 4, cc = g & 15, cs = cc ^ (r & 15);
            async16(Ablk + (size_t)r * DD + d0 + cs * 4,
                    &a_lds[(256 * i + 64 * w) * 4]);
        }
        // B: 1024 granules (16B = 8 bf16), 4 per thread
#pragma unroll
        for (int i = 0; i < 4; ++i) {
            int g = t + 256 * i;
            int r = g >> 3, cc = g & 7, cs = cc ^ (r & 7);
            async16(Bblk + (size_t)r * DD + d0 + cs * 8,
                    &b_lds[(256 * i + 64 * w) * 8]);
        }
        __syncthreads();   // staging drained

#pragma unroll
        for (int ks = 0; ks < 2; ++ks) {
            bf16x8 af[4], bfr[4];
#pragma unroll
            for (int mi = 0; mi < 4; ++mi) {
                int R  = m_off + mi * 16 + ml;
                int gB = 8 * ks + 2 * kg;           // even
                float4 lo = *(const float4*)&a_lds[R * BK + ((gB    ) ^ (R & 15)) * 4];
                float4 hi4 = *(const float4*)&a_lds[R * BK + ((gB + 1) ^ (R & 15)) * 4];
                bf16x8 f;
                f[0] = (bf16)lo.x;  f[1] = (bf16)lo.y;
                f[2] = (bf16)lo.z;  f[3] = (bf16)lo.w;
                f[4] = (bf16)hi4.x; f[5] = (bf16)hi4.y;
                f[6] = (bf16)hi4.z; f[7] = (bf16)hi4.w;
                af[mi] = f;
            }
#pragma unroll
            for (int ni = 0; ni < 4; ++ni) {
                int R = n_off + ni * 16 + ml;
                int pos = (ks * 4 + kg) ^ (R & 7);
                bfr[ni] = *(const bf16x8*)&b_lds[R * BK + pos * 8];
            }
#pragma unroll
            for (int mi = 0; mi < 4; ++mi)
#pragma unroll
                for (int ni = 0; ni < 4; ++ni)
                    acc[mi][ni] = __builtin_amdgcn_mfma_f32_16x16x32_bf16(
                        af[mi], bfr[ni], acc[mi][ni], 0, 0, 0);
        }
    }

    // epilogue: tanh + v-weight; quad shuffle-reduce over 64 a's; direct
    // global store of partial[(b,s)*8 + a_tile*2 + n_half].
    float w1qa[4], va[4];
#pragma unroll
    for (int ni = 0; ni < 4; ++ni) {
        int a = a0 + n_off + ni * 16 + ml;
        w1qa[ni] = w1q[(size_t)b * AD + a];
        va[ni]   = v[a];
    }
    const int slot = a_tile * 2 + (w >> 1);
#pragma unroll
    for (int mi = 0; mi < 4; ++mi) {
#pragma unroll
        for (int reg = 0; reg < 4; ++reg) {
            float p = 0.f;
#pragma unroll
            for (int ni = 0; ni < 4; ++ni) {
                float x = acc[mi][ni][reg] + w1qa[ni];
                float th = 1.f - 2.f / (1.f + __expf(2.f * x));
                p = fmaf(th, va[ni], p);
            }
            p += __shfl_xor(p, 1);
            p += __shfl_xor(p, 2);
            p += __shfl_xor(p, 4);
            p += __shfl_xor(p, 8);
            if (ml == 0) {
                int row = m_off + mi * 16 + kg * 4 + reg;
                partial[((size_t)b * SS + s0 + row) * 8 + slot] = p;
            }
        }
    }
}

// ---------------- K2-fallback (round-2 style, no ws converts) -------------
#define FBK 32
#define FLDK (FBK + 8)
__global__ __launch_bounds__(256, 2)
void gemm_scores_fallback(const float* __restrict__ keys,
                          const float* __restrict__ W2,
                          const float* __restrict__ w1q,
                          const float* __restrict__ v,
                          float* __restrict__ partial) {
    __shared__ bf16 a_lds[BM][FLDK];
    __shared__ bf16 b_lds[BN][FLDK];
    __shared__ float s_red[BM];

    const int t    = threadIdx.x;
    const int lane = t & 63;
    const int w    = t >> 6;
    const int ml   = lane & 15;
    const int kg   = lane >> 4;
    const int b    = blockIdx.z;
    const int s0   = blockIdx.x * BM;
    const int a0   = blockIdx.y * BN;
    const int m_off = (w & 1) * 64;
    const int n_off = (w >> 1) * 64;

    const float* Ablk = keys + ((size_t)b * SS + s0) * DD;
    const float* Bblk = W2 + (size_t)a0 * DD;

    if (t < BM) s_red[t] = 0.f;

    floatx4 acc[4][4];
#pragma unroll
    for (int mi = 0; mi < 4; ++mi)
#pragma unroll
        for (int ni = 0; ni < 4; ++ni)
            acc[mi][ni] = (floatx4)(0.f);

    float4 ga[4], gb[4];
#pragma unroll
    for (int i = 0; i < 4; ++i) {
        int idx = t + 256 * i;
        int r = idx >> 3, c = idx & 7;
        ga[i] = *(const float4*)(Ablk + (size_t)r * DD + c * 4);
        gb[i] = *(const float4*)(Bblk + (size_t)r * DD + c * 4);
    }

    for (int chunk = 0; chunk < DD / FBK; ++chunk) {
        __syncthreads();
#pragma unroll
        for (int i = 0; i < 4; ++i) {
            int idx = t + 256 * i;
            int r = idx >> 3, c = idx & 7;
            bf16x4 pa, pb;
            pa[0] = (bf16)ga[i].x; pa[1] = (bf16)ga[i].y;
            pa[2] = (bf16)ga[i].z; pa[3] = (bf16)ga[i].w;
            pb[0] = (bf16)gb[i].x; pb[1] = (bf16)gb[i].y;
            pb[2] = (bf16)gb[i].z; pb[3] = (bf16)gb[i].w;
            *(bf16x4*)&a_lds[r][c * 4] = pa;
            *(bf16x4*)&b_lds[r][c * 4] = pb;
        }
        __syncthreads();
        if (chunk < DD / FBK - 1) {
            int d0 = (chunk + 1) * FBK;
#pragma unroll
            for (int i = 0; i < 4; ++i) {
                int idx = t + 256 * i;
                int r = idx >> 3, c = idx & 7;
                ga[i] = *(const float4*)(Ablk + (size_t)r * DD + d0 + c * 4);
                gb[i] = *(const float4*)(Bblk + (size_t)r * DD + d0 + c * 4);
            }
        }
        bf16x8 af[4], bfr[4];
#pragma unroll
        for (int mi = 0; mi < 4; ++mi)
            af[mi] = *(const bf16x8*)&a_lds[m_off + mi * 16 + ml][kg * 8];
#pragma unroll
        for (int ni = 0; ni < 4; ++ni)
            bfr[ni] = *(const bf16x8*)&b_lds[n_off + ni * 16 + ml][kg * 8];
#pragma unroll
        for (int mi = 0; mi < 4; ++mi)
#pragma unroll
            for (int ni = 0; ni < 4; ++ni)
                acc[mi][ni] = __builtin_amdgcn_mfma_f32_16x16x32_bf16(
                    af[mi], bfr[ni], acc[mi][ni], 0, 0, 0);
    }

    float w1qa[4], va[4];
#pragma unroll
    for (int ni = 0; ni < 4; ++ni) {
        int a = a0 + n_off + ni * 16 + ml;
        w1qa[ni] = w1q[(size_t)b * AD + a];
        va[ni]   = v[a];
    }
#pragma unroll
    for (int mi = 0; mi < 4; ++mi) {
#pragma unroll
        for (int reg = 0; reg < 4; ++reg) {
            float p = 0.f;
#pragma unroll
            for (int ni = 0; ni < 4; ++ni) {
                float x = acc[mi][ni][reg] + w1qa[ni];
                float th = 1.f - 2.f / (1.f + __expf(2.f * x));
                p = fmaf(th, va[ni], p);
            }
            p += __shfl_xor(p, 1);
            p += __shfl_xor(p, 2);
            p += __shfl_xor(p, 4);
            p += __shfl_xor(p, 8);
            if (ml == 0)
                atomicAdd(&s_red[m_off + mi * 16 + kg * 4 + reg], p);
        }
    }
    __syncthreads();
    if (t < BM)
        partial[(((size_t)b * SS) + s0 + t) * 8 + blockIdx.y * 2] = s_red[t];
}

// ---------------- K3: combine 8 partials + masked softmax over s ----------
__global__ void softmax_kernel(const float* __restrict__ partial,
                               const int* __restrict__ mask_i32,
                               const unsigned char* __restrict__ mask_u8,
                               const int* __restrict__ flag,
                               float* __restrict__ out) {
    const int b = blockIdx.x;
    const int t = threadIdx.x;
    __shared__ float rmax[4], rsum[4];
    const int wid = t >> 6, lane = t & 63;

    float sv[8]; int mv[8];
    const int bytes = (*flag != 0);
#pragma unroll
    for (int k = 0; k < 8; ++k) {
        int i = t + 256 * k;
        const float4* p4 = (const float4*)(partial + ((size_t)b * SS + i) * 8);
        float4 pa = p4[0], pb = p4[1];
        sv[k] = ((pa.x + pa.y) + (pa.z + pa.w)) + ((pb.x + pb.y) + (pb.z + pb.w));
        mv[k] = bytes ? (int)mask_u8[(size_t)b * SS + i]
                      : mask_i32[(size_t)b * SS + i];
    }

    float mx = -INFINITY;
#pragma unroll
    for (int k = 0; k < 8; ++k) mx = fmaxf(mx, mv[k] ? sv[k] : -INFINITY);
#pragma unroll
    for (int off = 32; off > 0; off >>= 1) mx = fmaxf(mx, __shfl_xor(mx, off));
    if (lane == 0) rmax[wid] = mx;
    __syncthreads();
    mx = fmaxf(fmaxf(rmax[0], rmax[1]), fmaxf(rmax[2], rmax[3]));

    float ev[8]; float sum = 0.f;
#pragma unroll
    for (int k = 0; k < 8; ++k) {
        ev[k] = mv[k] ? __expf(sv[k] - mx) : 0.f;
        sum += ev[k];
    }
#pragma unroll
    for (int off = 32; off > 0; off >>= 1) sum += __shfl_xor(sum, off);
    if (lane == 0) rsum[wid] = sum;
    __syncthreads();
    sum = (rsum[0] + rsum[1]) + (rsum[2] + rsum[3]);
    float inv = 1.f / sum;
#pragma unroll
    for (int k = 0; k < 8; ++k)
        out[(size_t)b * SS + t + 256 * k] = ev[k] * inv;
}

extern "C" void kernel_launch(void* const* d_in, const int* in_sizes, int n_in,
                              void* d_out, int out_size, void* d_ws, size_t ws_size,
                              hipStream_t stream) {
    const float* query = (const float*)d_in[0];
    const float* keys  = (const float*)d_in[1];
    const void*  mask  = d_in[2];
    const float* W1    = (const float*)d_in[3];
    const float* W2    = (const float*)d_in[4];
    const float* v     = (const float*)d_in[5];
    float* out = (float*)d_out;

    // ws layout (bytes): [flag 256][w1q 64K][partial 2M][W2b 0.5M]
    char* wsb = (char*)d_ws;
    int*   flag    = (int*)wsb;
    float* w1q     = (float*)(wsb + 256);
    float* partial = (float*)(wsb + 256 + 65536);
    bf16*  W2b     = (bf16*)(wsb + 256 + 65536 + 2097152);
    size_t need = 256 + 65536 + 2097152 + (size_t)AD * DD * 2;

    hipMemsetAsync(flag, 0, 4, stream);
    if (ws_size >= need) {
        prep_kernel<<<NCV + 64 + 4096, 256, 0, stream>>>(
            W2, W2b, (const unsigned char*)mask, flag, query, W1, w1q);
        gemm_scores_mfma<<<(SS / BM) * (AD / BN) * BB, 256, 0, stream>>>(
            keys, W2b, w1q, v, partial);
    } else {
        hipMemsetAsync(partial, 0, (size_t)BB * SS * 8 * 4, stream);
        prep_kernel<<<NCV + 64 + 4096, 256, 0, stream>>>(
            W2, W2b, (const unsigned char*)mask, flag, query, W1, w1q);
        gemm_scores_fallback<<<dim3(SS / BM, AD / BN, BB), 256, 0, stream>>>(
            keys, W2, w1q, v, partial);
    }
    softmax_kernel<<<BB, 256, 0, stream>>>(partial, (const int*)mask,
                                           (const unsigned char*)mask, flag, out);
}